// Round 1
// baseline (173.269 us; speedup 1.0000x reference)
//
#include <hip/hip_runtime.h>

#define NR    8192
#define FOUT  64
#define ALPHA 0.2f

__device__ inline unsigned enc_f32(float f) {
    unsigned u = __float_as_uint(f);
    return (u & 0x80000000u) ? ~u : (u | 0x80000000u);
}
__device__ inline float dec_f32(unsigned u) {
    return __uint_as_float((u & 0x80000000u) ? (u ^ 0x80000000u) : ~u);
}

// K1: h = X @ W (8192x128 @ 128x64), f1 = h@a1, f2 = h@a2, atomic f2max.
// 256 blocks x 256 thr. Each block: 32 rows. Wave w holds W[k in 32w..32w+32][c=lane]
// in registers; partial dot per row; cross-wave k-reduce via LDS.
__global__ __launch_bounds__(256) void k1_gemm(
    const float* __restrict__ X, const float* __restrict__ W, const float* __restrict__ a,
    float* __restrict__ H, float* __restrict__ F1, float* __restrict__ F2,
    unsigned* __restrict__ FM)
{
    __shared__ __align__(16) float xs[32 * 128];     // 16 KB
    __shared__ float part[32 * 4 * 64];              // 32 KB
    const int tid = threadIdx.x;
    const int w = tid >> 6, c = tid & 63;
    const int R0 = blockIdx.x * 32;

    float Wreg[32];
#pragma unroll
    for (int e = 0; e < 32; ++e) Wreg[e] = W[(w * 32 + e) * 64 + c];
#pragma unroll
    for (int q = 0; q < 16; ++q) { int idx = q * 256 + tid; xs[idx] = X[R0 * 128 + idx]; }
    __syncthreads();

    for (int r = 0; r < 32; ++r) {
        float acc = 0.f;
        const float* xr = &xs[r * 128 + w * 32];
#pragma unroll
        for (int e = 0; e < 32; ++e) acc = fmaf(xr[e], Wreg[e], acc);
        part[(r * 4 + w) * 64 + c] = acc;
    }
    __syncthreads();

    const float a1 = a[c], a2 = a[64 + c];
    for (int rr = 0; rr < 8; ++rr) {
        const int r = w * 8 + rr;
        const int i = R0 + r;
        float h = part[(r * 4 + 0) * 64 + c] + part[(r * 4 + 1) * 64 + c]
                + part[(r * 4 + 2) * 64 + c] + part[(r * 4 + 3) * 64 + c];
        H[i * 64 + c] = h;
        float v1 = h * a1, v2 = h * a2;
#pragma unroll
        for (int m = 32; m >= 1; m >>= 1) {
            v1 += __shfl_xor(v1, m, 64);
            v2 += __shfl_xor(v2, m, 64);
        }
        if (c == 0) { F1[i] = v1; F2[i] = v2; atomicMax(FM, enc_f32(v2)); }
    }
}

// K2a: rank[j] = #{j' : f2[j'] < f2[j]  or (== and j' < j)}   (exact, tie-broken)
// grid 256 = 32 j-tiles x 8 k-slices; integer atomicAdd partials (deterministic).
__global__ __launch_bounds__(256) void k2a_rank(
    const float* __restrict__ F2v, unsigned* __restrict__ RANK)
{
    __shared__ __align__(16) float f2s[1024];
    const int tid = threadIdx.x;
    const int bj = blockIdx.x & 31, bk = blockIdx.x >> 5;
    const int j = bj * 256 + tid;
    const float th = F2v[j];
#pragma unroll
    for (int q = 0; q < 4; ++q) f2s[q * 256 + tid] = F2v[bk * 1024 + q * 256 + tid];
    __syncthreads();
    unsigned cnt = 0;
    const int base = bk * 1024;
    for (int q = 0; q < 256; ++q) {
        float4 v = ((float4*)f2s)[q];
        int jj = base + q * 4;
        cnt += (unsigned)((v.x < th) | ((v.x == th) & ((jj + 0) < j)));
        cnt += (unsigned)((v.y < th) | ((v.y == th) & ((jj + 1) < j)));
        cnt += (unsigned)((v.z < th) | ((v.z == th) & ((jj + 2) < j)));
        cnt += (unsigned)((v.w < th) | ((v.w == th) & ((jj + 3) < j)));
    }
    atomicAdd(&RANK[j], cnt);
}

// K2b: scatter into rank order; P/Q factors (all <= 1).
__global__ __launch_bounds__(256) void k2b_scatter(
    const float* __restrict__ F2v, const unsigned* __restrict__ RANK,
    const unsigned* __restrict__ FM,
    float* __restrict__ SF2, int* __restrict__ PERM,
    float* __restrict__ PS, float* __restrict__ QS)
{
    const int j = blockIdx.x * 256 + threadIdx.x;
    const float f = F2v[j];
    const unsigned r = RANK[j];
    const float fm = dec_f32(*FM);
    const float d = f - fm;
    SF2[r] = f;
    PERM[r] = j;
    PS[r] = expf(d);
    QS[r] = expf(ALPHA * d);
}

// K3: per-chunk (32 ranks) sums of P_t*h and Q_t*h (64-wide) + scalar sums.
__global__ __launch_bounds__(256) void k3_chunks(
    const float* __restrict__ H, const int* __restrict__ PERM,
    const float* __restrict__ PS, const float* __restrict__ QS,
    float* __restrict__ CHP, float* __restrict__ CHQ,
    float* __restrict__ chp, float* __restrict__ chq)
{
    __shared__ float redP[256], redQ[256], reds[8];
    const int tid = threadIdx.x;
    const int w = tid >> 6, c = tid & 63;
    const int b = blockIdx.x;
    float accP = 0.f, accQ = 0.f, sp = 0.f, sq = 0.f;
    for (int e = 0; e < 8; ++e) {
        const int t = b * 32 + w * 8 + e;
        const int j = PERM[t];
        const float P = PS[t], Q = QS[t];
        const float hv = H[j * 64 + c];
        accP = fmaf(P, hv, accP);
        accQ = fmaf(Q, hv, accQ);
        sp += P; sq += Q;
    }
    redP[w * 64 + c] = accP;
    redQ[w * 64 + c] = accQ;
    if (c == 0) { reds[w] = sp; reds[4 + w] = sq; }
    __syncthreads();
    if (w == 0) {
        float p = redP[c] + redP[64 + c] + redP[128 + c] + redP[192 + c];
        float q = redQ[c] + redQ[64 + c] + redQ[128 + c] + redQ[192 + c];
        CHP[b * 64 + c] = p;
        CHQ[b * 64 + c] = q;
        if (c == 0) {
            chp[b] = reds[0] + reds[1] + reds[2] + reds[3];
            chq[b] = reds[4] + reds[5] + reds[6] + reds[7];
        }
    }
}

// K4: exclusive scan over 256 chunks (in-place), totals at index 256.
__global__ __launch_bounds__(256) void k4_scan(
    float* __restrict__ CHP, float* __restrict__ CHQ,
    float* __restrict__ chp, float* __restrict__ chq)
{
    const int tid = threadIdx.x;
    if (tid < 64) {
        float acc = 0.f;
        for (int b = 0; b < 256; ++b) { float v = CHP[b * 64 + tid]; CHP[b * 64 + tid] = acc; acc += v; }
        CHP[256 * 64 + tid] = acc;
    } else if (tid < 128) {
        const int c = tid - 64;
        float acc = 0.f;
        for (int b = 0; b < 256; ++b) { float v = CHQ[b * 64 + c]; CHQ[b * 64 + c] = acc; acc += v; }
        CHQ[256 * 64 + c] = acc;
    } else if (tid == 128) {
        float acc = 0.f;
        for (int b = 0; b < 256; ++b) { float v = chp[b]; chp[b] = acc; acc += v; }
        chp[256] = acc;
    } else if (tid == 192) {
        float acc = 0.f;
        for (int b = 0; b < 256; ++b) { float v = chq[b]; chq[b] = acc; acc += v; }
        chq[256] = acc;
    }
}

// K6: per row: t = rank of -f1_i (binary search), chunk lookup + <=32-term exact
// correction, combine, elu. One wave per row.
__global__ __launch_bounds__(256) void k6_rows(
    const float* __restrict__ H, const float* __restrict__ F1,
    const unsigned* __restrict__ FM, const float* __restrict__ SF2,
    const int* __restrict__ PERM, const float* __restrict__ PS, const float* __restrict__ QS,
    const float* __restrict__ CHP, const float* __restrict__ CHQ,
    const float* __restrict__ chp, const float* __restrict__ chq,
    float* __restrict__ OUT)
{
    const int tid = threadIdx.x;
    const int w = tid >> 6, c = tid & 63;
    const int i = blockIdx.x * 4 + w;

    const float fm = dec_f32(*FM);
    const float f1 = F1[i];
    const float s = f1 + fm;
    const float m = fmaxf(s, ALPHA * s);          // row max of lrelu scores
    const float A = expf(s - m);                  // <= 1
    const float B = expf(ALPHA * s - m);          // <= 1
    const float th = -f1;

    int lo = 0, hi = 8192;
    while (lo < hi) {
        int mid = (lo + hi) >> 1;
        if (SF2[mid] < th) lo = mid + 1; else hi = mid;
    }
    const int t = lo;
    const int b = t >> 5;
    const int t0 = b << 5;

    float qv = CHQ[b * 64 + c];   // exclusive prefix of Q*h at chunk start
    float pv = 0.f;               // partial P*h over [t0, t)
    float qs = chq[b], ps = 0.f;
    for (int tt = t0; tt < t; ++tt) {
        const int j = PERM[tt];
        const float P = PS[tt], Q = QS[tt];
        const float hv = H[j * 64 + c];
        qv = fmaf(Q, hv, qv);
        pv = fmaf(P, hv, pv);
        qs += Q; ps += P;
    }
    const float Pvec = CHP[256 * 64 + c] - (CHP[b * 64 + c] + pv);  // suffix P*h
    const float pden = chp[256] - (chp[b] + ps);                    // suffix P
    const float num = A * Pvec + B * qv;
    const float den = A * pden + B * qs;
    const float feat = num / den;
    OUT[i * 64 + c] = feat > 0.f ? feat : expm1f(feat);
}

extern "C" void kernel_launch(void* const* d_in, const int* in_sizes, int n_in,
                              void* d_out, int out_size, void* d_ws, size_t ws_size,
                              hipStream_t stream) {
    const float* X = (const float*)d_in[0];   // 8192 x 128
    const float* W = (const float*)d_in[1];   // 128 x 64
    const float* a = (const float*)d_in[2];   // 128 x 1
    float* OUT = (float*)d_out;               // 8192 x 64

    float* ws = (float*)d_ws;
    float*    H    = ws;                         // 524288
    float*    F1   = H + 524288;                 // 8192
    float*    F2   = F1 + 8192;                  // 8192
    unsigned* RANK = (unsigned*)(F2 + 8192);     // 8192
    unsigned* FM   = RANK + 8192;                // 16 (1 used)
    float*    SF2  = (float*)(FM + 16);          // 8192
    int*      PERM = (int*)(SF2 + 8192);         // 8192
    float*    PS   = (float*)(PERM + 8192);      // 8192
    float*    QS   = PS + 8192;                  // 8192
    float*    CHP  = QS + 8192;                  // 257*64
    float*    CHQ  = CHP + 257 * 64;             // 257*64
    float*    chp  = CHQ + 257 * 64;             // 257
    float*    chq  = chp + 257;                  // 257
    // total ~2.4 MB of ws

    hipMemsetAsync(RANK, 0, (8192 + 16) * sizeof(unsigned), stream);
    k1_gemm<<<256, 256, 0, stream>>>(X, W, a, H, F1, F2, FM);
    k2a_rank<<<256, 256, 0, stream>>>(F2, RANK);
    k2b_scatter<<<32, 256, 0, stream>>>(F2, RANK, FM, SF2, PERM, PS, QS);
    k3_chunks<<<256, 256, 0, stream>>>(H, PERM, PS, QS, CHP, CHQ, chp, chq);
    k4_scan<<<1, 256, 0, stream>>>(CHP, CHQ, chp, chq);
    k6_rows<<<2048, 256, 0, stream>>>(H, F1, FM, SF2, PERM, PS, QS, CHP, CHQ, chp, chq, OUT);
}

// Round 2
// 81.984 us; speedup vs baseline: 2.1135x; 2.1135x over previous
//
#include <hip/hip_runtime.h>

#define NR    8192
#define FOUT  64
#define ALPHA 0.2f

__device__ inline unsigned enc_f32(float f) {
    unsigned u = __float_as_uint(f);
    return (u & 0x80000000u) ? ~u : (u | 0x80000000u);
}
__device__ inline float dec_f32(unsigned u) {
    return __uint_as_float((u & 0x80000000u) ? (u ^ 0x80000000u) : ~u);
}

// K1: h = X @ W (8192x128 @ 128x64), f1 = h@a1, f2 = h@a2, block-reduced atomic f2max.
__global__ __launch_bounds__(256) void k1_gemm(
    const float* __restrict__ X, const float* __restrict__ W, const float* __restrict__ a,
    float* __restrict__ H, float* __restrict__ F1, float* __restrict__ F2,
    unsigned* __restrict__ FM)
{
    __shared__ __align__(16) float xs[32 * 128];     // 16 KB
    __shared__ float part[32 * 4 * 64];              // 32 KB
    __shared__ float wmax[4];
    const int tid = threadIdx.x;
    const int w = tid >> 6, c = tid & 63;
    const int R0 = blockIdx.x * 32;

    float Wreg[32];
#pragma unroll
    for (int e = 0; e < 32; ++e) Wreg[e] = W[(w * 32 + e) * 64 + c];
#pragma unroll
    for (int q = 0; q < 16; ++q) { int idx = q * 256 + tid; xs[idx] = X[R0 * 128 + idx]; }
    __syncthreads();

    for (int r = 0; r < 32; ++r) {
        float acc = 0.f;
        const float* xr = &xs[r * 128 + w * 32];
#pragma unroll
        for (int e = 0; e < 32; ++e) acc = fmaf(xr[e], Wreg[e], acc);
        part[(r * 4 + w) * 64 + c] = acc;
    }
    __syncthreads();

    const float a1 = a[c], a2 = a[64 + c];
    float lmax = -3.0e38f;
    for (int rr = 0; rr < 8; ++rr) {
        const int r = w * 8 + rr;
        const int i = R0 + r;
        float h = part[(r * 4 + 0) * 64 + c] + part[(r * 4 + 1) * 64 + c]
                + part[(r * 4 + 2) * 64 + c] + part[(r * 4 + 3) * 64 + c];
        H[i * 64 + c] = h;
        float v1 = h * a1, v2 = h * a2;
#pragma unroll
        for (int m = 32; m >= 1; m >>= 1) {
            v1 += __shfl_xor(v1, m, 64);
            v2 += __shfl_xor(v2, m, 64);
        }
        if (c == 0) { F1[i] = v1; F2[i] = v2; }
        lmax = fmaxf(lmax, v2);          // all lanes hold the full v2 sum
    }
    if (c == 0) wmax[w] = lmax;
    __syncthreads();
    if (tid == 0) {
        float m = fmaxf(fmaxf(wmax[0], wmax[1]), fmaxf(wmax[2], wmax[3]));
        atomicMax(FM, enc_f32(m));       // ONE device atomic per block (256 total)
    }
}

// K2a: rank[j] = #{j' : f2[j'] < f2[j]  or (== and j' < j)}   (exact, tie-broken)
__global__ __launch_bounds__(256) void k2a_rank(
    const float* __restrict__ F2v, unsigned* __restrict__ RANK)
{
    __shared__ __align__(16) float f2s[1024];
    const int tid = threadIdx.x;
    const int bj = blockIdx.x & 31, bk = blockIdx.x >> 5;
    const int j = bj * 256 + tid;
    const float th = F2v[j];
#pragma unroll
    for (int q = 0; q < 4; ++q) f2s[q * 256 + tid] = F2v[bk * 1024 + q * 256 + tid];
    __syncthreads();
    unsigned cnt = 0;
    const int base = bk * 1024;
    for (int q = 0; q < 256; ++q) {
        float4 v = ((float4*)f2s)[q];
        int jj = base + q * 4;
        cnt += (unsigned)((v.x < th) | ((v.x == th) & ((jj + 0) < j)));
        cnt += (unsigned)((v.y < th) | ((v.y == th) & ((jj + 1) < j)));
        cnt += (unsigned)((v.z < th) | ((v.z == th) & ((jj + 2) < j)));
        cnt += (unsigned)((v.w < th) | ((v.w == th) & ((jj + 3) < j)));
    }
    atomicAdd(&RANK[j], cnt);
}

// K2b: scatter into rank order; P/Q factors (all <= 1).
__global__ __launch_bounds__(256) void k2b_scatter(
    const float* __restrict__ F2v, const unsigned* __restrict__ RANK,
    const unsigned* __restrict__ FM,
    float* __restrict__ SF2, int* __restrict__ PERM,
    float* __restrict__ PS, float* __restrict__ QS)
{
    const int j = blockIdx.x * 256 + threadIdx.x;
    const float f = F2v[j];
    const unsigned r = RANK[j];
    const float fm = dec_f32(*FM);
    const float d = f - fm;
    SF2[r] = f;
    PERM[r] = j;
    PS[r] = expf(d);
    QS[r] = expf(ALPHA * d);
}

// K3: per-chunk (32 ranks) sums of P_t*h and Q_t*h (64-wide) + scalar sums.
__global__ __launch_bounds__(256) void k3_chunks(
    const float* __restrict__ H, const int* __restrict__ PERM,
    const float* __restrict__ PS, const float* __restrict__ QS,
    float* __restrict__ CHP, float* __restrict__ CHQ,
    float* __restrict__ chp, float* __restrict__ chq)
{
    __shared__ float redP[256], redQ[256], reds[8];
    const int tid = threadIdx.x;
    const int w = tid >> 6, c = tid & 63;
    const int b = blockIdx.x;
    float accP = 0.f, accQ = 0.f, sp = 0.f, sq = 0.f;
    for (int e = 0; e < 8; ++e) {
        const int t = b * 32 + w * 8 + e;
        const int j = PERM[t];
        const float P = PS[t], Q = QS[t];
        const float hv = H[j * 64 + c];
        accP = fmaf(P, hv, accP);
        accQ = fmaf(Q, hv, accQ);
        sp += P; sq += Q;
    }
    redP[w * 64 + c] = accP;
    redQ[w * 64 + c] = accQ;
    if (c == 0) { reds[w] = sp; reds[4 + w] = sq; }
    __syncthreads();
    if (w == 0) {
        float p = redP[c] + redP[64 + c] + redP[128 + c] + redP[192 + c];
        float q = redQ[c] + redQ[64 + c] + redQ[128 + c] + redQ[192 + c];
        CHP[b * 64 + c] = p;
        CHQ[b * 64 + c] = q;
        if (c == 0) {
            chp[b] = reds[0] + reds[1] + reds[2] + reds[3];
            chq[b] = reds[4] + reds[5] + reds[6] + reds[7];
        }
    }
}

// K4: parallel exclusive scan over 256 chunks. Blocks 0..63: column b of CHP+CHQ;
// block 64: scalar chp/chq. Hillis-Steele in LDS (8 steps), totals at index 256.
__device__ void scan256(float* __restrict__ g, int stride, float* __restrict__ s)
{
    const int t = threadIdx.x;
    const float v = g[t * stride];
    s[t] = v;
    __syncthreads();
    for (int off = 1; off < 256; off <<= 1) {
        float u = (t >= off) ? s[t - off] : 0.f;
        __syncthreads();
        s[t] += u;
        __syncthreads();
    }
    const float exc = (t > 0) ? s[t - 1] : 0.f;
    g[t * stride] = exc;
    if (t == 255) g[256 * stride] = s[255];
    __syncthreads();
}

__global__ __launch_bounds__(256) void k4_scan(
    float* __restrict__ CHP, float* __restrict__ CHQ,
    float* __restrict__ chp, float* __restrict__ chq)
{
    __shared__ float s[256];
    const int b = blockIdx.x;
    if (b < 64) {
        scan256(CHP + b, 64, s);
        scan256(CHQ + b, 64, s);
    } else {
        scan256(chp, 1, s);
        scan256(chq, 1, s);
    }
}

// K6: per row: t = rank of -f1_i (binary search), chunk lookup + <=32-term exact
// correction, combine, elu. One wave per row.
__global__ __launch_bounds__(256) void k6_rows(
    const float* __restrict__ H, const float* __restrict__ F1,
    const unsigned* __restrict__ FM, const float* __restrict__ SF2,
    const int* __restrict__ PERM, const float* __restrict__ PS, const float* __restrict__ QS,
    const float* __restrict__ CHP, const float* __restrict__ CHQ,
    const float* __restrict__ chp, const float* __restrict__ chq,
    float* __restrict__ OUT)
{
    const int tid = threadIdx.x;
    const int w = tid >> 6, c = tid & 63;
    const int i = blockIdx.x * 4 + w;

    const float fm = dec_f32(*FM);
    const float f1 = F1[i];
    const float s = f1 + fm;
    const float m = fmaxf(s, ALPHA * s);          // row max of lrelu scores
    const float A = expf(s - m);                  // <= 1
    const float B = expf(ALPHA * s - m);          // <= 1
    const float th = -f1;

    int lo = 0, hi = 8192;
    while (lo < hi) {
        int mid = (lo + hi) >> 1;
        if (SF2[mid] < th) lo = mid + 1; else hi = mid;
    }
    const int t = lo;
    const int b = t >> 5;
    const int t0 = b << 5;

    float qv = CHQ[b * 64 + c];   // exclusive prefix of Q*h at chunk start
    float pv = 0.f;               // partial P*h over [t0, t)
    float qs = chq[b], ps = 0.f;
    for (int tt = t0; tt < t; ++tt) {
        const int j = PERM[tt];
        const float P = PS[tt], Q = QS[tt];
        const float hv = H[j * 64 + c];
        qv = fmaf(Q, hv, qv);
        pv = fmaf(P, hv, pv);
        qs += Q; ps += P;
    }
    const float Pvec = CHP[256 * 64 + c] - (CHP[b * 64 + c] + pv);  // suffix P*h
    const float pden = chp[256] - (chp[b] + ps);                    // suffix P
    const float num = A * Pvec + B * qv;
    const float den = A * pden + B * qs;
    const float feat = num / den;
    OUT[i * 64 + c] = feat > 0.f ? feat : expm1f(feat);
}

extern "C" void kernel_launch(void* const* d_in, const int* in_sizes, int n_in,
                              void* d_out, int out_size, void* d_ws, size_t ws_size,
                              hipStream_t stream) {
    const float* X = (const float*)d_in[0];   // 8192 x 128
    const float* W = (const float*)d_in[1];   // 128 x 64
    const float* a = (const float*)d_in[2];   // 128 x 1
    float* OUT = (float*)d_out;               // 8192 x 64

    float* ws = (float*)d_ws;
    float*    H    = ws;                         // 524288
    float*    F1   = H + 524288;                 // 8192
    float*    F2   = F1 + 8192;                  // 8192
    unsigned* RANK = (unsigned*)(F2 + 8192);     // 8192
    unsigned* FM   = RANK + 8192;                // 16 (1 used)
    float*    SF2  = (float*)(FM + 16);          // 8192
    int*      PERM = (int*)(SF2 + 8192);         // 8192
    float*    PS   = (float*)(PERM + 8192);      // 8192
    float*    QS   = PS + 8192;                  // 8192
    float*    CHP  = QS + 8192;                  // 257*64
    float*    CHQ  = CHP + 257 * 64;             // 257*64
    float*    chp  = CHQ + 257 * 64;             // 257
    float*    chq  = chp + 257;                  // 257

    hipMemsetAsync(RANK, 0, (8192 + 16) * sizeof(unsigned), stream);
    k1_gemm<<<256, 256, 0, stream>>>(X, W, a, H, F1, F2, FM);
    k2a_rank<<<256, 256, 0, stream>>>(F2, RANK);
    k2b_scatter<<<32, 256, 0, stream>>>(F2, RANK, FM, SF2, PERM, PS, QS);
    k3_chunks<<<256, 256, 0, stream>>>(H, PERM, PS, QS, CHP, CHQ, chp, chq);
    k4_scan<<<65, 256, 0, stream>>>(CHP, CHQ, chp, chq);
    k6_rows<<<2048, 256, 0, stream>>>(H, F1, FM, SF2, PERM, PS, QS, CHP, CHQ, chp, chq, OUT);
}

// Round 3
// 76.169 us; speedup vs baseline: 2.2748x; 1.0763x over previous
//
#include <hip/hip_runtime.h>

#define NR    8192
#define FOUT  64
#define ALPHA 0.2f

// K1: h = X @ W (8192x128 @ 128x64), f1 = h@a1, f2 = h@a2, per-block f2 max
// to BMAX (plain store — no atomics, no pre-zeroed state anywhere).
__global__ __launch_bounds__(256) void k1_gemm(
    const float* __restrict__ X, const float* __restrict__ W, const float* __restrict__ a,
    float* __restrict__ H, float* __restrict__ F1, float* __restrict__ F2,
    float* __restrict__ BMAX)
{
    __shared__ __align__(16) float xs[32 * 128];     // 16 KB
    __shared__ float part[32 * 4 * 64];              // 32 KB
    __shared__ float wmax[4];
    const int tid = threadIdx.x;
    const int w = tid >> 6, c = tid & 63;
    const int R0 = blockIdx.x * 32;

    float Wreg[32];
#pragma unroll
    for (int e = 0; e < 32; ++e) Wreg[e] = W[(w * 32 + e) * 64 + c];
#pragma unroll
    for (int q = 0; q < 16; ++q) { int idx = q * 256 + tid; xs[idx] = X[R0 * 128 + idx]; }
    __syncthreads();

    for (int r = 0; r < 32; ++r) {
        float acc = 0.f;
        const float* xr = &xs[r * 128 + w * 32];
#pragma unroll
        for (int e = 0; e < 32; ++e) acc = fmaf(xr[e], Wreg[e], acc);
        part[(r * 4 + w) * 64 + c] = acc;
    }
    __syncthreads();

    const float a1 = a[c], a2 = a[64 + c];
    float lmax = -3.0e38f;
    for (int rr = 0; rr < 8; ++rr) {
        const int r = w * 8 + rr;
        const int i = R0 + r;
        float h = part[(r * 4 + 0) * 64 + c] + part[(r * 4 + 1) * 64 + c]
                + part[(r * 4 + 2) * 64 + c] + part[(r * 4 + 3) * 64 + c];
        H[i * 64 + c] = h;
        float v1 = h * a1, v2 = h * a2;
#pragma unroll
        for (int m = 32; m >= 1; m >>= 1) {
            v1 += __shfl_xor(v1, m, 64);
            v2 += __shfl_xor(v2, m, 64);
        }
        if (c == 0) { F1[i] = v1; F2[i] = v2; }
        lmax = fmaxf(lmax, v2);          // all lanes hold the full v2 sum
    }
    if (c == 0) wmax[w] = lmax;
    __syncthreads();
    if (tid == 0)
        BMAX[blockIdx.x] = fmaxf(fmaxf(wmax[0], wmax[1]), fmaxf(wmax[2], wmax[3]));
}

// K2a: rank partials. Block (bj,bk): count over k-slice bk for 256 j's.
// Plain store to RANKP[bk][j] — deterministic, no init, no atomics.
__global__ __launch_bounds__(256) void k2a_rank(
    const float* __restrict__ F2v, unsigned* __restrict__ RANKP)
{
    __shared__ __align__(16) float f2s[1024];
    const int tid = threadIdx.x;
    const int bj = blockIdx.x & 31, bk = blockIdx.x >> 5;
    const int j = bj * 256 + tid;
    const float th = F2v[j];
#pragma unroll
    for (int q = 0; q < 4; ++q) f2s[q * 256 + tid] = F2v[bk * 1024 + q * 256 + tid];
    __syncthreads();
    unsigned cnt = 0;
    const int base = bk * 1024;
    for (int q = 0; q < 256; ++q) {
        float4 v = ((float4*)f2s)[q];
        int jj = base + q * 4;
        cnt += (unsigned)((v.x < th) | ((v.x == th) & ((jj + 0) < j)));
        cnt += (unsigned)((v.y < th) | ((v.y == th) & ((jj + 1) < j)));
        cnt += (unsigned)((v.z < th) | ((v.z == th) & ((jj + 2) < j)));
        cnt += (unsigned)((v.w < th) | ((v.w == th) & ((jj + 3) < j)));
    }
    RANKP[bk * NR + j] = cnt;
}

// K2b: sum rank partials, reduce BMAX -> fm, scatter into rank order, P/Q factors.
__global__ __launch_bounds__(256) void k2b_scatter(
    const float* __restrict__ F2v, const unsigned* __restrict__ RANKP,
    const float* __restrict__ BMAX,
    float* __restrict__ SF2, int* __restrict__ PERM,
    float* __restrict__ PS, float* __restrict__ QS, float* __restrict__ FMf)
{
    __shared__ float sm[256];
    const int tid = threadIdx.x;
    sm[tid] = BMAX[tid];
    __syncthreads();
    for (int off = 128; off > 0; off >>= 1) {
        if (tid < off) sm[tid] = fmaxf(sm[tid], sm[tid + off]);
        __syncthreads();
    }
    const float fm = sm[0];

    const int j = blockIdx.x * 256 + tid;
    unsigned r = 0;
#pragma unroll
    for (int s = 0; s < 8; ++s) r += RANKP[s * NR + j];
    const float f = F2v[j];
    const float d = f - fm;
    SF2[r] = f;
    PERM[r] = j;
    PS[r] = expf(d);
    QS[r] = expf(ALPHA * d);
    if (blockIdx.x == 0 && tid == 0) FMf[0] = fm;
}

// K3: per-chunk (32 ranks) sums of P_t*h and Q_t*h (64-wide) + scalar sums.
__global__ __launch_bounds__(256) void k3_chunks(
    const float* __restrict__ H, const int* __restrict__ PERM,
    const float* __restrict__ PS, const float* __restrict__ QS,
    float* __restrict__ CHP, float* __restrict__ CHQ,
    float* __restrict__ chp, float* __restrict__ chq)
{
    __shared__ float redP[256], redQ[256], reds[8];
    const int tid = threadIdx.x;
    const int w = tid >> 6, c = tid & 63;
    const int b = blockIdx.x;
    float accP = 0.f, accQ = 0.f, sp = 0.f, sq = 0.f;
    for (int e = 0; e < 8; ++e) {
        const int t = b * 32 + w * 8 + e;
        const int j = PERM[t];
        const float P = PS[t], Q = QS[t];
        const float hv = H[j * 64 + c];
        accP = fmaf(P, hv, accP);
        accQ = fmaf(Q, hv, accQ);
        sp += P; sq += Q;
    }
    redP[w * 64 + c] = accP;
    redQ[w * 64 + c] = accQ;
    if (c == 0) { reds[w] = sp; reds[4 + w] = sq; }
    __syncthreads();
    if (w == 0) {
        float p = redP[c] + redP[64 + c] + redP[128 + c] + redP[192 + c];
        float q = redQ[c] + redQ[64 + c] + redQ[128 + c] + redQ[192 + c];
        CHP[b * 64 + c] = p;
        CHQ[b * 64 + c] = q;
        if (c == 0) {
            chp[b] = reds[0] + reds[1] + reds[2] + reds[3];
            chq[b] = reds[4] + reds[5] + reds[6] + reds[7];
        }
    }
}

// K4: parallel exclusive scan over 256 chunks. Blocks 0..63: column b of CHP+CHQ;
// block 64: scalar chp/chq. Hillis-Steele in LDS (8 steps), totals at index 256.
__device__ void scan256(float* __restrict__ g, int stride, float* __restrict__ s)
{
    const int t = threadIdx.x;
    const float v = g[t * stride];
    s[t] = v;
    __syncthreads();
    for (int off = 1; off < 256; off <<= 1) {
        float u = (t >= off) ? s[t - off] : 0.f;
        __syncthreads();
        s[t] += u;
        __syncthreads();
    }
    const float exc = (t > 0) ? s[t - 1] : 0.f;
    g[t * stride] = exc;
    if (t == 255) g[256 * stride] = s[255];
    __syncthreads();
}

__global__ __launch_bounds__(256) void k4_scan(
    float* __restrict__ CHP, float* __restrict__ CHQ,
    float* __restrict__ chp, float* __restrict__ chq)
{
    __shared__ float s[256];
    const int b = blockIdx.x;
    if (b < 64) {
        scan256(CHP + b, 64, s);
        scan256(CHQ + b, 64, s);
    } else {
        scan256(chp, 1, s);
        scan256(chq, 1, s);
    }
}

// K6: per row: t = rank of -f1_i (binary search), chunk lookup + <=32-term exact
// correction, combine, elu. One wave per row.
__global__ __launch_bounds__(256) void k6_rows(
    const float* __restrict__ H, const float* __restrict__ F1,
    const float* __restrict__ FMf, const float* __restrict__ SF2,
    const int* __restrict__ PERM, const float* __restrict__ PS, const float* __restrict__ QS,
    const float* __restrict__ CHP, const float* __restrict__ CHQ,
    const float* __restrict__ chp, const float* __restrict__ chq,
    float* __restrict__ OUT)
{
    const int tid = threadIdx.x;
    const int w = tid >> 6, c = tid & 63;
    const int i = blockIdx.x * 4 + w;

    const float fm = FMf[0];
    const float f1 = F1[i];
    const float s = f1 + fm;
    const float m = fmaxf(s, ALPHA * s);          // row max of lrelu scores
    const float A = expf(s - m);                  // <= 1
    const float B = expf(ALPHA * s - m);          // <= 1
    const float th = -f1;

    int lo = 0, hi = 8192;
    while (lo < hi) {
        int mid = (lo + hi) >> 1;
        if (SF2[mid] < th) lo = mid + 1; else hi = mid;
    }
    const int t = lo;
    const int b = t >> 5;
    const int t0 = b << 5;

    float qv = CHQ[b * 64 + c];   // exclusive prefix of Q*h at chunk start
    float pv = 0.f;               // partial P*h over [t0, t)
    float qs = chq[b], ps = 0.f;
    for (int tt = t0; tt < t; ++tt) {
        const int j = PERM[tt];
        const float P = PS[tt], Q = QS[tt];
        const float hv = H[j * 64 + c];
        qv = fmaf(Q, hv, qv);
        pv = fmaf(P, hv, pv);
        qs += Q; ps += P;
    }
    const float Pvec = CHP[256 * 64 + c] - (CHP[b * 64 + c] + pv);  // suffix P*h
    const float pden = chp[256] - (chp[b] + ps);                    // suffix P
    const float num = A * Pvec + B * qv;
    const float den = A * pden + B * qs;
    const float feat = num / den;
    OUT[i * 64 + c] = feat > 0.f ? feat : expm1f(feat);
}

extern "C" void kernel_launch(void* const* d_in, const int* in_sizes, int n_in,
                              void* d_out, int out_size, void* d_ws, size_t ws_size,
                              hipStream_t stream) {
    const float* X = (const float*)d_in[0];   // 8192 x 128
    const float* W = (const float*)d_in[1];   // 128 x 64
    const float* a = (const float*)d_in[2];   // 128 x 1
    float* OUT = (float*)d_out;               // 8192 x 64

    float* ws = (float*)d_ws;
    float*    H     = ws;                          // 524288
    float*    F1    = H + 524288;                  // 8192
    float*    F2    = F1 + 8192;                   // 8192
    unsigned* RANKP = (unsigned*)(F2 + 8192);      // 8 * 8192
    float*    BMAX  = (float*)(RANKP + 8 * 8192);  // 256
    float*    FMf   = BMAX + 256;                  // 16 (1 used)
    float*    SF2   = FMf + 16;                    // 8192
    int*      PERM  = (int*)(SF2 + 8192);          // 8192
    float*    PS    = (float*)(PERM + 8192);       // 8192
    float*    QS    = PS + 8192;                   // 8192
    float*    CHP   = QS + 8192;                   // 257*64
    float*    CHQ   = CHP + 257 * 64;              // 257*64
    float*    chp   = CHQ + 257 * 64;              // 257
    float*    chq   = chp + 257;                   // 257

    k1_gemm<<<256, 256, 0, stream>>>(X, W, a, H, F1, F2, BMAX);
    k2a_rank<<<256, 256, 0, stream>>>(F2, RANKP);
    k2b_scatter<<<32, 256, 0, stream>>>(F2, RANKP, BMAX, SF2, PERM, PS, QS, FMf);
    k3_chunks<<<256, 256, 0, stream>>>(H, PERM, PS, QS, CHP, CHQ, chp, chq);
    k4_scan<<<65, 256, 0, stream>>>(CHP, CHQ, chp, chq);
    k6_rows<<<2048, 256, 0, stream>>>(H, F1, FMf, SF2, PERM, PS, QS, CHP, CHQ, chp, chq, OUT);
}